// Round 4
// baseline (5456.021 us; speedup 1.0000x reference)
//
#include <hip/hip_runtime.h>
#include <stdint.h>

// LSTM rollout, pairwise column-split persistent blocks, weights fully on-chip.
// B=8192, HORIZON=64, F=64, ORDER=16, K=256, 4K=1024.
// Pair (bid, bid^128) handles batch rows p*64..p*64+63 (p=bid&127); half hf=bid>>7
// owns output columns {gate*256 + hf*128 .. +128} i.e. hidden units hf*128..+128.
// Per block weights = 352KB: k-steps 0..7 in VGPRs (128 regs/wave), 8..10 in LDS (96KB).
// Per step: blocks exchange their h-half (16KB bf16) + pred partial via global
// double-buffered slots with agent-scope release/acquire flags (same-XCD pair).
// K rows: 0..63 x_t, 64..79 yp (newest first), 80..335 h, 336..351 pad(0).

typedef short v8s __attribute__((ext_vector_type(8)));
typedef float v4f __attribute__((ext_vector_type(4)));

#define NKS 11
#define WS_FLAGS    720896u          // 256 uint flags (zeroed by prep_w each launch)
#define WS_SLOTS    (1u << 20)       // exchange slots base
#define SLOT_STRIDE 16896u           // 16KB h + 256B pred + pad
#define SLOT_PRED   16384u

__device__ __forceinline__ unsigned bf16u(float f) {
  unsigned u = __float_as_uint(f);
  return (u + 0x7FFFu + ((u >> 16) & 1u)) >> 16;   // RNE fp32->bf16
}
__device__ __forceinline__ float sigm(float x) {
  return __builtin_amdgcn_rcpf(1.f + __expf(-x));
}
__device__ __forceinline__ float tanh_(float x) {
  return 1.f - 2.f * __builtin_amdgcn_rcpf(1.f + __expf(2.f * x));
}
// Swizzled A-LDS address for element (m,k): 1KB tile per (mt,ks), lane-linear.
__device__ __forceinline__ int a_addr(int m, int k) {
  return (((m >> 4) * NKS + (k >> 5)) << 10)
       + ((((k >> 3) & 3) * 16 + (m & 15)) << 4)
       + ((k & 7) << 1);
}

// ---------------- weight swizzle + flag init (once per launch) ----------------
// wsw[(nt*11+ks)*64+lane] = 8 bf16: B[k=ks*32+(lane>>4)*8+j][n=nt*16+(lane&15)]
__global__ void prep_w(const float* __restrict__ ker, const float* __restrict__ rec,
                       char* __restrict__ ws) {
  int tid = blockIdx.x * 256 + threadIdx.x;
  if (tid < 45056) {
    uint4* wsw = (uint4*)ws;
    int lane = tid & 63;
    int rest = tid >> 6;
    int ks = rest % NKS;
    int nt = rest / NKS;
    int n  = nt * 16 + (lane & 15);
    int k0 = ks * 32 + ((lane >> 4) & 3) * 8;
    unsigned h[8];
    #pragma unroll
    for (int j = 0; j < 8; ++j) {
      int k = k0 + j;
      float v = 0.f;
      if (k < 80)       v = ker[k * 1024 + n];
      else if (k < 336) v = rec[(k - 80) * 1024 + n];
      h[j] = bf16u(v);
    }
    uint4 o;
    o.x = h[0] | (h[1] << 16); o.y = h[2] | (h[3] << 16);
    o.z = h[4] | (h[5] << 16); o.w = h[6] | (h[7] << 16);
    wsw[tid] = o;
  } else if (tid < 45312) {
    ((unsigned*)(ws + WS_FLAGS))[tid - 45056] = 0u;   // flags must be re-zeroed (ws poisoned 0xAA)
  }
}

// ---------------- main persistent kernel ----------------
__global__ __launch_bounds__(512, 2)
void lstm_main(const float* __restrict__ x, const float* __restrict__ y0,
               const float* __restrict__ bias, const float* __restrict__ dw,
               const float* __restrict__ db, const v8s* __restrict__ wv,
               char* __restrict__ ws, float* __restrict__ out) {
  __shared__ __align__(16) char a_lds[NKS * 4 * 1024];   // 44KB swizzled A (M=64)
  __shared__ __align__(16) char w_lds[98304];            // ks 8..10 weights (96KB)
  __shared__ float predbuf[64][8];
  __shared__ float predmine[64];
  __shared__ float predf2[64];

  const int tid  = threadIdx.x;
  const int lane = tid & 63;
  const int wave = __builtin_amdgcn_readfirstlane(tid >> 6);
  const int l15  = lane & 15;
  const int quad = lane >> 4;
  const int bid  = blockIdx.x;
  const int hf   = bid >> 7;          // column half
  const int p    = bid & 127;         // pair id
  const int partner = bid ^ 128;
  const int b0   = p * 64;

  unsigned* flags = (unsigned*)(ws + WS_FLAGS);

  // zero A (h rows 0 at t=0; pad rows 336..351 stay 0 forever)
  for (int i = tid; i < NKS * 4 * 256; i += 512) ((unsigned*)a_lds)[i] = 0;

  // wave owns hidden units [hf*128 + wave*16, +16); gate g column tile:
  int wb[4];
  float bias_v[4];
  #pragma unroll
  for (int g = 0; g < 4; ++g) {
    int nt = g * 16 + hf * 8 + wave;
    wb[g] = nt * (NKS * 64);
    bias_v[g] = bias[nt * 16 + l15];
  }
  const int u_loc  = wave * 16 + l15;     // unit within half
  const int u_glob = hf * 128 + u_loc;    // global hidden unit
  const int kk = 80 + u_glob;             // own h row in A
  const float dwv = dw[u_glob];
  const float dbv = db[0];

  // register-resident weights: ks 0..7
  v8s wreg[8][4];
  #pragma unroll
  for (int ks = 0; ks < 8; ++ks)
    #pragma unroll
    for (int g = 0; g < 4; ++g)
      wreg[ks][g] = wv[wb[g] + ks * 64 + lane];

  // LDS-resident weights: ks 8..10 (per-wave private 12KB)
  {
    char* wlp = w_lds + wave * 12288 + (lane << 4);
    #pragma unroll
    for (int ks2 = 0; ks2 < 3; ++ks2)
      #pragma unroll
      for (int g = 0; g < 4; ++g)
        *(v8s*)(wlp + ks2 * 4096 + g * 1024) = wv[wb[g] + (8 + ks2) * 64 + lane];
  }

  float cst[4][4];
  #pragma unroll
  for (int mt = 0; mt < 4; ++mt)
    #pragma unroll
    for (int r = 0; r < 4; ++r) cst[mt][r] = 0.f;

  const int ms = tid >> 3;     // batch row 0..63
  const int jj = tid & 7;

  __syncthreads();

  #pragma unroll 1
  for (int t = 0; t < 64; ++t) {
    // ---- S0: wait for partner's h(t-1) ----
    if (t > 0) {
      if (tid == 0) {
        unsigned* pf = flags + partner;
        while (__hip_atomic_load(pf, __ATOMIC_RELAXED, __HIP_MEMORY_SCOPE_AGENT) < (unsigned)t)
          __builtin_amdgcn_s_sleep(2);
      }
      __syncthreads();
      __threadfence();   // acquire: invalidate L1/L2 so partner slot reads are fresh
    }
    // ---- S1: stage x(t); read yp olds; stage partner h(t-1); merge pred(t-1) ----
    {
      const float* xp = x + (((size_t)(b0 + ms) * 64 + t) << 6) + (jj << 3);
      float4 xa = ((const float4*)xp)[0];
      float4 xb = ((const float4*)xp)[1];
      uint4 w4;
      w4.x = bf16u(xa.x) | (bf16u(xa.y) << 16);
      w4.y = bf16u(xa.z) | (bf16u(xa.w) << 16);
      w4.z = bf16u(xb.x) | (bf16u(xb.y) << 16);
      w4.w = bf16u(xb.z) | (bf16u(xb.w) << 16);
      *(uint4*)(a_lds + a_addr(ms, jj * 8)) = w4;
    }
    unsigned short q0, q1;
    if (t == 0) {
      q0 = (unsigned short)bf16u(y0[(b0 + ms) * 16 + 2 * jj]);
      q1 = (unsigned short)bf16u(y0[(b0 + ms) * 16 + 2 * jj + 1]);
    } else {
      q0 = *(const unsigned short*)(a_lds + a_addr(ms, 64 + 2 * jj));
      q1 = *(const unsigned short*)(a_lds + a_addr(ms, 64 + 2 * jj + 1));
      const char* pslot = ws + WS_SLOTS
          + (size_t)(((p * 2 + (1 - hf)) * 2) + ((t - 1) & 1)) * SLOT_STRIDE;
      uint4 h0 = *(const uint4*)(pslot + ms * 256 + (jj << 5));
      uint4 h1 = *(const uint4*)(pslot + ms * 256 + (jj << 5) + 16);
      int k0 = 80 + (1 - hf) * 128 + (jj << 4);
      *(uint4*)(a_lds + a_addr(ms, k0)) = h0;        // 8 consecutive k, 16B aligned
      *(uint4*)(a_lds + a_addr(ms, k0 + 8)) = h1;
      if (tid < 64) {
        float pp = predmine[tid] + *(const float*)(pslot + SLOT_PRED + (tid << 2)) + dbv;
        predf2[tid] = pp;
        if (hf == 0) out[((size_t)(b0 + tid) << 6) + (t - 1)] = pp;
      }
    }
    __syncthreads();
    // ---- S2: yp shift-in writes ----
    if (t == 0) {
      *(unsigned short*)(a_lds + a_addr(ms, 64 + 2 * jj))     = q0;
      *(unsigned short*)(a_lds + a_addr(ms, 64 + 2 * jj + 1)) = q1;
    } else {
      if (jj < 7) {
        *(unsigned short*)(a_lds + a_addr(ms, 64 + 2 * jj + 1)) = q0;
        *(unsigned short*)(a_lds + a_addr(ms, 64 + 2 * jj + 2)) = q1;
      } else {
        *(unsigned short*)(a_lds + a_addr(ms, 79)) = q0;
      }
      if (jj == 0)
        *(unsigned short*)(a_lds + a_addr(ms, 64)) = (unsigned short)bf16u(predf2[ms]);
    }
    __syncthreads();

    // ---- P3: GEMM  z[64,512] = inp[64,352] @ Whalf[352,512] ----
    v4f acc[4][4];
    #pragma unroll
    for (int mt = 0; mt < 4; ++mt)
      #pragma unroll
      for (int g = 0; g < 4; ++g) acc[mt][g] = v4f{0.f, 0.f, 0.f, 0.f};

    #pragma unroll
    for (int ks = 0; ks < 8; ++ks) {
      v8s a0 = *(const v8s*)(a_lds + ((0 * NKS + ks) << 10) + (lane << 4));
      v8s a1 = *(const v8s*)(a_lds + ((1 * NKS + ks) << 10) + (lane << 4));
      v8s a2 = *(const v8s*)(a_lds + ((2 * NKS + ks) << 10) + (lane << 4));
      v8s a3 = *(const v8s*)(a_lds + ((3 * NKS + ks) << 10) + (lane << 4));
      #pragma unroll
      for (int g = 0; g < 4; ++g) {
        acc[0][g] = __builtin_amdgcn_mfma_f32_16x16x32_bf16(a0, wreg[ks][g], acc[0][g], 0, 0, 0);
        acc[1][g] = __builtin_amdgcn_mfma_f32_16x16x32_bf16(a1, wreg[ks][g], acc[1][g], 0, 0, 0);
        acc[2][g] = __builtin_amdgcn_mfma_f32_16x16x32_bf16(a2, wreg[ks][g], acc[2][g], 0, 0, 0);
        acc[3][g] = __builtin_amdgcn_mfma_f32_16x16x32_bf16(a3, wreg[ks][g], acc[3][g], 0, 0, 0);
      }
    }
    #pragma unroll
    for (int ks2 = 0; ks2 < 3; ++ks2) {
      const int ks = 8 + ks2;
      v8s a0 = *(const v8s*)(a_lds + ((0 * NKS + ks) << 10) + (lane << 4));
      v8s a1 = *(const v8s*)(a_lds + ((1 * NKS + ks) << 10) + (lane << 4));
      v8s a2 = *(const v8s*)(a_lds + ((2 * NKS + ks) << 10) + (lane << 4));
      v8s a3 = *(const v8s*)(a_lds + ((3 * NKS + ks) << 10) + (lane << 4));
      v8s bw[4];
      #pragma unroll
      for (int g = 0; g < 4; ++g)
        bw[g] = *(const v8s*)(w_lds + wave * 12288 + ks2 * 4096 + g * 1024 + (lane << 4));
      #pragma unroll
      for (int g = 0; g < 4; ++g) {
        acc[0][g] = __builtin_amdgcn_mfma_f32_16x16x32_bf16(a0, bw[g], acc[0][g], 0, 0, 0);
        acc[1][g] = __builtin_amdgcn_mfma_f32_16x16x32_bf16(a1, bw[g], acc[1][g], 0, 0, 0);
        acc[2][g] = __builtin_amdgcn_mfma_f32_16x16x32_bf16(a2, bw[g], acc[2][g], 0, 0, 0);
        acc[3][g] = __builtin_amdgcn_mfma_f32_16x16x32_bf16(a3, bw[g], acc[3][g], 0, 0, 0);
      }
    }
    __syncthreads();   // all A reads done before h-row writes

    // ---- P4: gates, c/h update, h -> A-LDS + exchange slot, pred partials ----
    char* myslot = ws + WS_SLOTS + (size_t)(((p * 2 + hf) * 2) + (t & 1)) * SLOT_STRIDE;
    float padd[4][4];
    #pragma unroll
    for (int mt = 0; mt < 4; ++mt) {
      #pragma unroll
      for (int r = 0; r < 4; ++r) {
        float zi = acc[mt][0][r] + bias_v[0];
        float zf = acc[mt][1][r] + bias_v[1];
        float zg = acc[mt][2][r] + bias_v[2];
        float zo = acc[mt][3][r] + bias_v[3];
        float is = sigm(zi), fs = sigm(zf), gs = tanh_(zg), os = sigm(zo);
        float cn = fs * cst[mt][r] + is * gs;
        cst[mt][r] = cn;
        float hh = os * tanh_(cn);
        int m = mt * 16 + quad * 4 + r;
        unsigned short hb = (unsigned short)bf16u(hh);
        *(unsigned short*)(a_lds + a_addr(m, kk)) = hb;
        *(unsigned short*)(myslot + m * 256 + (u_loc << 1)) = hb;
        padd[mt][r] = hh * dwv;
      }
    }
    #pragma unroll
    for (int mt = 0; mt < 4; ++mt) {
      #pragma unroll
      for (int r = 0; r < 4; ++r) {
        float pv = padd[mt][r];
        pv += __shfl_xor(pv, 1);
        pv += __shfl_xor(pv, 2);
        pv += __shfl_xor(pv, 4);
        pv += __shfl_xor(pv, 8);
        if (l15 == 0) predbuf[mt * 16 + quad * 4 + r][wave] = pv;
      }
    }
    __threadfence();          // flush my h slot writes toward LLC
    __syncthreads();
    if (tid < 64) {
      float s = 0.f;
      #pragma unroll
      for (int w = 0; w < 8; ++w) s += predbuf[tid][w];
      predmine[tid] = s;
      *(float*)(myslot + SLOT_PRED + (tid << 2)) = s;
      __threadfence();        // flush pred partial
    }
    __syncthreads();
    if (tid == 0)
      __hip_atomic_store(flags + bid, (unsigned)(t + 1),
                         __ATOMIC_RELEASE, __HIP_MEMORY_SCOPE_AGENT);
  }

  // ---- epilogue: merge + write pred(63) ----
  if (hf == 0) {
    if (tid == 0) {
      unsigned* pf = flags + partner;
      while (__hip_atomic_load(pf, __ATOMIC_RELAXED, __HIP_MEMORY_SCOPE_AGENT) < 64u)
        __builtin_amdgcn_s_sleep(2);
    }
    __syncthreads();
    __threadfence();
    if (tid < 64) {
      const char* pslot = ws + WS_SLOTS + (size_t)(((p * 2 + 1) * 2) + 1) * SLOT_STRIDE;
      float pp = predmine[tid] + *(const float*)(pslot + SLOT_PRED + (tid << 2)) + dbv;
      out[((size_t)(b0 + tid) << 6) + 63] = pp;
    }
  }
}

extern "C" void kernel_launch(void* const* d_in, const int* in_sizes, int n_in,
                              void* d_out, int out_size, void* d_ws, size_t ws_size,
                              hipStream_t stream) {
  const float* x    = (const float*)d_in[0];
  const float* y0   = (const float*)d_in[1];
  const float* ker  = (const float*)d_in[2];
  const float* rec  = (const float*)d_in[3];
  const float* bias = (const float*)d_in[4];
  const float* dw   = (const float*)d_in[5];
  const float* db   = (const float*)d_in[6];

  // 45056 weight entries + 256 flag zeroes = 45312 threads
  prep_w<<<dim3(177), dim3(256), 0, stream>>>(ker, rec, (char*)d_ws);
  lstm_main<<<dim3(256), dim3(512), 0, stream>>>(x, y0, bias, dw, db,
                                                 (const v8s*)d_ws, (char*)d_ws,
                                                 (float*)d_out);
}

// Round 5
// 1540.256 us; speedup vs baseline: 3.5423x; 3.5423x over previous
//
#include <hip/hip_runtime.h>
#include <stdint.h>

// LSTM autoregressive rollout, batch-split persistent blocks. R5.
// B=8192, HORIZON=64, F=64, ORDER=16, K=256, 4K=1024.
// Block = 32 batch rows, 512 threads (8 waves, 2/SIMD). 256 blocks = 1/CU.
// Weights bf16, pre-swizzled to B-fragment order in d_ws (704KB).
// Residency: ks0 in regs (32 VGPR/wave), ks1-2 in LDS (128KB).
// Stream ks3..10 via rolling 2-buffer register pipeline (16 loads in flight,
// issued at loop top + 2-ks-ahead reloads). STRICT reg budget <=256/wave
// (R1-R3 lesson: demand ~290 -> ~35 regs spilled in the K-loop = 118MB scratch
// traffic = the whole 1430us wall; WRITE_SIZE is the diagnostic).
// K rows: 0..63 x_t, 64..79 yp (newest first), 80..335 h, 336..351 pad(0).

typedef short v8s __attribute__((ext_vector_type(8)));
typedef float v4f __attribute__((ext_vector_type(4)));

#define NKS 11
#define NKCOL 1024

__device__ __forceinline__ unsigned bf16u(float f) {
  unsigned u = __float_as_uint(f);
  return (u + 0x7FFFu + ((u >> 16) & 1u)) >> 16;   // RNE fp32->bf16
}
__device__ __forceinline__ float sigm(float x) {
  return __builtin_amdgcn_rcpf(1.f + __expf(-x));
}
__device__ __forceinline__ float tanh_(float x) {
  return 1.f - 2.f * __builtin_amdgcn_rcpf(1.f + __expf(2.f * x));
}
// Swizzled A-LDS address for element (m,k): 1KB tile per (mt,ks), lane-linear.
__device__ __forceinline__ int a_addr(int m, int k) {
  return (((m >> 4) * NKS + (k >> 5)) << 10)
       + ((((k >> 3) & 3) * 16 + (m & 15)) << 4)
       + ((k & 7) << 1);
}

// ---------------- weight swizzle prep (once per launch) ----------------
// wsw[(nt*11+ks)*64+lane] = 8 bf16: B[k=ks*32+(lane>>4)*8+j][n=nt*16+(lane&15)]
__global__ void prep_w(const float* __restrict__ ker, const float* __restrict__ rec,
                       uint4* __restrict__ wsw) {
  int tid = blockIdx.x * 256 + threadIdx.x;     // 0 .. 45055
  int lane = tid & 63;
  int rest = tid >> 6;
  int ks = rest % NKS;
  int nt = rest / NKS;
  int n  = nt * 16 + (lane & 15);
  int k0 = ks * 32 + ((lane >> 4) & 3) * 8;
  unsigned h[8];
  #pragma unroll
  for (int j = 0; j < 8; ++j) {
    int k = k0 + j;
    float v = 0.f;
    if (k < 80)       v = ker[k * NKCOL + n];
    else if (k < 336) v = rec[(k - 80) * NKCOL + n];
    h[j] = bf16u(v);
  }
  uint4 o;
  o.x = h[0] | (h[1] << 16); o.y = h[2] | (h[3] << 16);
  o.z = h[4] | (h[5] << 16); o.w = h[6] | (h[7] << 16);
  wsw[tid] = o;
}

// ---------------- main persistent kernel ----------------
__global__ __launch_bounds__(512, 2)
void lstm_main(const float* __restrict__ x, const float* __restrict__ y0,
               const float* __restrict__ bias, const float* __restrict__ dw,
               const float* __restrict__ db, const v8s* __restrict__ wv,
               float* __restrict__ out) {
  __shared__ __align__(16) char a_lds[2 * NKS * 1024];   // 22528 B swizzled A
  __shared__ __align__(16) char w_lds[131072];           // ks1-2 weight cache
  __shared__ float predbuf[32][8];
  __shared__ float predf[32];

  const int tid  = threadIdx.x;
  const int lane = tid & 63;
  const int wave = __builtin_amdgcn_readfirstlane(tid >> 6);
  const int l15  = lane & 15;
  const int quad = lane >> 4;
  const int b0   = blockIdx.x * 32;

  // zero A (h rows must be 0 at t=0; pad rows 336..351 stay 0 forever)
  for (int i = tid; i < 2 * NKS * 256; i += 512) ((unsigned*)a_lds)[i] = 0;

  // wave owns output ntiles: ln = gate*2 + s -> global ntile g*16 + wave*2 + s
  int wb[8];          // wave-uniform -> SGPR
  float bias_v[8];
  #pragma unroll
  for (int ln = 0; ln < 8; ++ln) {
    int g = ln >> 1, s = ln & 1;
    int ntg = g * 16 + wave * 2 + s;
    wb[ln] = ntg * (NKS * 64);
    bias_v[ln] = bias[ntg * 16 + l15];
  }
  float dw_v0 = dw[wave * 32 + l15];
  float dw_v1 = dw[wave * 32 + 16 + l15];
  const float dbv = db[0];

  // register-resident weights: ks0 only (32 VGPRs)
  v8s wreg[8];
  #pragma unroll
  for (int ln = 0; ln < 8; ++ln) wreg[ln] = wv[wb[ln] + lane];

  // LDS-resident weights: ks1-2 (per-wave private 16KB)
  char* wl = w_lds + wave * 16384 + (lane << 4);
  #pragma unroll
  for (int ks2 = 0; ks2 < 2; ++ks2)
    #pragma unroll
    for (int ln = 0; ln < 8; ++ln)
      *(v8s*)(wl + ks2 * 8192 + ln * 1024) = wv[wb[ln] + (1 + ks2) * 64 + lane];

  float cst[2][2][4];
  #pragma unroll
  for (int mt = 0; mt < 2; ++mt)
    #pragma unroll
    for (int s = 0; s < 2; ++s)
      #pragma unroll
      for (int r = 0; r < 4; ++r) cst[mt][s][r] = 0.f;

  const int ms_x = tid >> 3;          // waves 0-3: batch row for x staging
  const int kq8  = tid & 7;
  const int ms_y = (tid - 256) >> 3;  // waves 4-7: yp shift row
  const int jj   = (tid - 256) & 7;

  // preload x(t=0)
  float4 xpa, xpb;
  if (tid < 256) {
    const float* xp = x + ((size_t)((b0 + ms_x) * 64 + 0)) * 64 + kq8 * 8;
    xpa = ((const float4*)xp)[0];
    xpb = ((const float4*)xp)[1];
  }

  __syncthreads();

  #pragma unroll 1
  for (int t = 0; t < 64; ++t) {
    // ---- top: issue streamed-weight prefetch ks3 -> bufA, ks4 -> bufB ----
    // (16 loads in flight through P1/P2; first use ~1.5K cyc later)
    v8s bufA[8], bufB[8];
    #pragma unroll
    for (int ln = 0; ln < 8; ++ln) bufA[ln] = wv[wb[ln] + 3 * 64 + lane];
    #pragma unroll
    for (int ln = 0; ln < 8; ++ln) bufB[ln] = wv[wb[ln] + 4 * 64 + lane];

    // ---- P1: yp read phase (waves 4-7) ----
    unsigned short q0 = 0, q1 = 0;
    float pin = 0.f;
    if (tid >= 256) {
      if (t == 0) {
        q0 = (unsigned short)bf16u(y0[(b0 + ms_y) * 16 + 2 * jj]);
        q1 = (unsigned short)bf16u(y0[(b0 + ms_y) * 16 + 2 * jj + 1]);
      } else {
        q0 = *(const unsigned short*)(a_lds + a_addr(ms_y, 64 + 2 * jj));
        q1 = *(const unsigned short*)(a_lds + a_addr(ms_y, 64 + 2 * jj + 1));
        pin = predf[ms_y];
      }
    }
    __syncthreads();
    // ---- P2: write phase ----
    if (tid < 256) {
      uint4 w4;
      w4.x = bf16u(xpa.x) | (bf16u(xpa.y) << 16);
      w4.y = bf16u(xpa.z) | (bf16u(xpa.w) << 16);
      w4.z = bf16u(xpb.x) | (bf16u(xpb.y) << 16);
      w4.w = bf16u(xpb.z) | (bf16u(xpb.w) << 16);
      *(uint4*)(a_lds + a_addr(ms_x, kq8 * 8)) = w4;
    } else {
      if (t == 0) {
        *(unsigned short*)(a_lds + a_addr(ms_y, 64 + 2 * jj))     = q0;
        *(unsigned short*)(a_lds + a_addr(ms_y, 64 + 2 * jj + 1)) = q1;
      } else {
        if (jj < 7) {
          *(unsigned short*)(a_lds + a_addr(ms_y, 64 + 2 * jj + 1)) = q0;
          *(unsigned short*)(a_lds + a_addr(ms_y, 64 + 2 * jj + 2)) = q1;
        } else {
          *(unsigned short*)(a_lds + a_addr(ms_y, 79)) = q0;
        }
        if (jj == 0)
          *(unsigned short*)(a_lds + a_addr(ms_y, 64)) = (unsigned short)bf16u(pin);
      }
    }
    __syncthreads();

    // ---- P3: GEMM  z[32,1024] = inp[32,352] @ W[352,1024] ----
    v4f acc[2][8];
    #pragma unroll
    for (int mt = 0; mt < 2; ++mt)
      #pragma unroll
      for (int ln = 0; ln < 8; ++ln) acc[mt][ln] = v4f{0.f, 0.f, 0.f, 0.f};

    // ks0: register weights
    {
      v8s a0 = *(const v8s*)(a_lds + (lane << 4));
      v8s a1 = *(const v8s*)(a_lds + (NKS << 10) + (lane << 4));
      #pragma unroll
      for (int ln = 0; ln < 8; ++ln) {
        acc[0][ln] = __builtin_amdgcn_mfma_f32_16x16x32_bf16(a0, wreg[ln], acc[0][ln], 0, 0, 0);
        acc[1][ln] = __builtin_amdgcn_mfma_f32_16x16x32_bf16(a1, wreg[ln], acc[1][ln], 0, 0, 0);
      }
    }
    // ks1-2: LDS weights
    #pragma unroll
    for (int ks = 1; ks < 3; ++ks) {
      v8s a0 = *(const v8s*)(a_lds + (ks << 10) + (lane << 4));
      v8s a1 = *(const v8s*)(a_lds + ((NKS + ks) << 10) + (lane << 4));
      #pragma unroll
      for (int ln = 0; ln < 8; ++ln) {
        v8s bw = *(const v8s*)(wl + (ks - 1) * 8192 + ln * 1024);
        acc[0][ln] = __builtin_amdgcn_mfma_f32_16x16x32_bf16(a0, bw, acc[0][ln], 0, 0, 0);
        acc[1][ln] = __builtin_amdgcn_mfma_f32_16x16x32_bf16(a1, bw, acc[1][ln], 0, 0, 0);
      }
    }
    // ks3..10: streamed, rolling 2-buffer pipeline (reload 2 ks ahead)
    #pragma unroll
    for (int ks = 3; ks < NKS; ++ks) {
      v8s a0 = *(const v8s*)(a_lds + (ks << 10) + (lane << 4));
      v8s a1 = *(const v8s*)(a_lds + ((NKS + ks) << 10) + (lane << 4));
      if (ks & 1) {   // odd ks -> bufA
        #pragma unroll
        for (int ln = 0; ln < 8; ++ln) {
          acc[0][ln] = __builtin_amdgcn_mfma_f32_16x16x32_bf16(a0, bufA[ln], acc[0][ln], 0, 0, 0);
          acc[1][ln] = __builtin_amdgcn_mfma_f32_16x16x32_bf16(a1, bufA[ln], acc[1][ln], 0, 0, 0);
        }
        if (ks + 2 < NKS) {
          #pragma unroll
          for (int ln = 0; ln < 8; ++ln) bufA[ln] = wv[wb[ln] + (ks + 2) * 64 + lane];
        }
      } else {        // even ks -> bufB
        #pragma unroll
        for (int ln = 0; ln < 8; ++ln) {
          acc[0][ln] = __builtin_amdgcn_mfma_f32_16x16x32_bf16(a0, bufB[ln], acc[0][ln], 0, 0, 0);
          acc[1][ln] = __builtin_amdgcn_mfma_f32_16x16x32_bf16(a1, bufB[ln], acc[1][ln], 0, 0, 0);
        }
        if (ks + 2 < NKS) {
          #pragma unroll
          for (int ln = 0; ln < 8; ++ln) bufB[ln] = wv[wb[ln] + (ks + 2) * 64 + lane];
        }
      }
    }
    __syncthreads();   // all A reads done before h-row writes

    // x(t+1) prefetch — overlaps gate math, lands before next P2
    if (tid < 256 && t < 63) {
      const float* xp = x + ((size_t)((b0 + ms_x) * 64 + t + 1)) * 64 + kq8 * 8;
      xpa = ((const float4*)xp)[0];
      xpb = ((const float4*)xp)[1];
    }

    // ---- P4: gates, c/h update, h->A, pred partials ----
    float padd[2][4];
    #pragma unroll
    for (int mt = 0; mt < 2; ++mt)
      #pragma unroll
      for (int r = 0; r < 4; ++r) padd[mt][r] = 0.f;

    #pragma unroll
    for (int mt = 0; mt < 2; ++mt) {
      #pragma unroll
      for (int s = 0; s < 2; ++s) {
        const int kk = 80 + wave * 32 + s * 16 + l15;
        #pragma unroll
        for (int r = 0; r < 4; ++r) {
          float zi = acc[mt][0 + s][r] + bias_v[0 + s];
          float zf = acc[mt][2 + s][r] + bias_v[2 + s];
          float zg = acc[mt][4 + s][r] + bias_v[4 + s];
          float zo = acc[mt][6 + s][r] + bias_v[6 + s];
          float is = sigm(zi), fs = sigm(zf), gs = tanh_(zg), os = sigm(zo);
          float cn = fs * cst[mt][s][r] + is * gs;
          cst[mt][s][r] = cn;
          float hh = os * tanh_(cn);
          int m = mt * 16 + quad * 4 + r;
          *(unsigned short*)(a_lds + a_addr(m, kk)) = (unsigned short)bf16u(hh);
          float dwv = (s == 0) ? dw_v0 : dw_v1;
          padd[mt][r] += hh * dwv;
        }
      }
    }
    #pragma unroll
    for (int mt = 0; mt < 2; ++mt) {
      #pragma unroll
      for (int r = 0; r < 4; ++r) {
        float p = padd[mt][r];
        p += __shfl_xor(p, 1);
        p += __shfl_xor(p, 2);
        p += __shfl_xor(p, 4);
        p += __shfl_xor(p, 8);
        if (l15 == 0) predbuf[mt * 16 + quad * 4 + r][wave] = p;
      }
    }
    __syncthreads();
    // ---- P5: finalize pred, write output ----
    if (tid < 32) {
      float p = dbv;
      #pragma unroll
      for (int w = 0; w < 8; ++w) p += predbuf[tid][w];
      out[(size_t)(b0 + tid) * 64 + t] = p;
      predf[tid] = p;
    }
    __syncthreads();
  }
}

extern "C" void kernel_launch(void* const* d_in, const int* in_sizes, int n_in,
                              void* d_out, int out_size, void* d_ws, size_t ws_size,
                              hipStream_t stream) {
  const float* x    = (const float*)d_in[0];
  const float* y0   = (const float*)d_in[1];
  const float* ker  = (const float*)d_in[2];
  const float* rec  = (const float*)d_in[3];
  const float* bias = (const float*)d_in[4];
  const float* dw   = (const float*)d_in[5];
  const float* db   = (const float*)d_in[6];

  prep_w<<<dim3(176), dim3(256), 0, stream>>>(ker, rec, (uint4*)d_ws);
  lstm_main<<<dim3(256), dim3(512), 0, stream>>>(x, y0, bias, dw, db,
                                                 (const v8s*)d_ws, (float*)d_out);
}